// Round 1
// baseline (717.418 us; speedup 1.0000x reference)
//
#include <hip/hip_runtime.h>

// Network: 2-layer minimal-GRU (T=1000 sequential steps, B=512) + FC + log_softmax.
// Strategy: one wave per batch element (latency-bound recurrence); weights in
// per-lane VGPRs; u=[x,h] broadcast from LDS; x streamed via double-buffered
// LDS chunks with register-staged prefetch one chunk ahead.

constexpr int FBINS  = 40;
constexpr int L1     = 32;
constexpr int L2     = 20;
constexpr int L3     = 16;
constexpr int NCLASS = 10;
constexpr int T      = 1000;

constexpr int CH     = 40;          // timesteps per LDS chunk
constexpr int NCHUNK = T / CH;      // 25
constexpr int CHDW   = CH * FBINS;  // 1600 dwords per chunk
constexpr int NLD    = CHDW / 64;   // 25 dword loads per lane per chunk

__global__ __launch_bounds__(64) void gru_net_kernel(
    const float* __restrict__ xg,
    const float* __restrict__ wz1, const float* __restrict__ bz1g,
    const float* __restrict__ wh1, const float* __restrict__ bh1g,
    const float* __restrict__ wz2, const float* __restrict__ bz2g,
    const float* __restrict__ wh2, const float* __restrict__ bh2g,
    const float* __restrict__ w3,  const float* __restrict__ b3g,
    const float* __restrict__ w4,  const float* __restrict__ b4g,
    float* __restrict__ outg)
{
    __shared__ alignas(16) float xA[CHDW];
    __shared__ alignas(16) float xB[CHDW];
    __shared__ alignas(16) float hbuf[64];   // [0..31]=h1, [32..51]=h2

    const int lane = threadIdx.x;
    const int b    = blockIdx.x;
    const float* xb = xg + (size_t)b * (size_t)(T * FBINS);

    // ---- per-lane weight columns in registers ----
    // GRU1: lane j<32 -> w_zx1[:, j]; lane 32+j -> w_hx1[:, j]
    float w1[FBINS + L1];
    float bias1;
    {
        const int j = lane & 31;
        const float* wp = (lane < 32) ? wz1 : wh1;
        #pragma unroll
        for (int k = 0; k < FBINS + L1; ++k) w1[k] = wp[k * L1 + j];
        bias1 = (lane < 32) ? bz1g[j] : bh1g[j];
    }
    // GRU2: lane j<20 -> w_zx2[:, j]; lane 32+j (j<20) -> w_hx2[:, j]
    float w2[L1 + L2];
    float bias2;
    {
        const int j0 = lane & 31;
        const int jj = (j0 < L2) ? j0 : 0;   // clamp unused lanes (no OOB)
        const float* wp = (lane < 32) ? wz2 : wh2;
        #pragma unroll
        for (int k = 0; k < L1 + L2; ++k) w2[k] = wp[k * L2 + jj];
        bias2 = (lane < 32) ? bz2g[jj] : bh2g[jj];
    }

    hbuf[lane] = 0.0f;
    float h1 = 0.0f, h2 = 0.0f;

    // ---- x-stream staging: global -> regs -> LDS, one chunk ahead ----
    float stage[NLD];
    auto load_stage = [&](int c) {
        const float* src = xb + c * CHDW;
        #pragma unroll
        for (int i = 0; i < NLD; ++i) stage[i] = src[i * 64 + lane];
    };
    auto write_stage = [&](float* buf) {
        #pragma unroll
        for (int i = 0; i < NLD; ++i) buf[i * 64 + lane] = stage[i];
    };

    constexpr float LOG2E = 1.4426950408889634f;
    constexpr float LN2   = 0.6931471805599453f;

    auto step = [&](const float* xs) {
        // ---- GRU layer 1: lanes 0..31 compute z_j, lanes 32..63 compute g_j
        float acc = bias1;
        #pragma unroll
        for (int k = 0; k < FBINS; ++k) acc = fmaf(xs[k], w1[k], acc);
        #pragma unroll
        for (int k = 0; k < L1; ++k)    acc = fmaf(hbuf[k], w1[FBINS + k], acc);
        // sigmoid for z-lanes; tanh(a) = 2*sigmoid(2a)-1 for g-lanes
        float arg = (lane < 32) ? acc : (acc + acc);
        float e   = __builtin_amdgcn_exp2f(-arg * LOG2E);
        float sg  = __builtin_amdgcn_rcpf(1.0f + e);
        float val = (lane < 32) ? sg : fmaf(2.0f, sg, -1.0f);
        float pr  = __shfl_xor(val, 32);           // z-lane gets g, g-lane gets z
        if (lane < 32) {
            h1 = fmaf(val, pr - h1, h1);           // (1-z)h + zg
            hbuf[lane] = h1;
        }
        // ---- GRU layer 2: u2 = [h1(32), h2(20)] = hbuf[0..51]
        float acc2 = bias2;
        #pragma unroll
        for (int k = 0; k < L1 + L2; ++k) acc2 = fmaf(hbuf[k], w2[k], acc2);
        float arg2 = (lane < 32) ? acc2 : (acc2 + acc2);
        float e2   = __builtin_amdgcn_exp2f(-arg2 * LOG2E);
        float sg2  = __builtin_amdgcn_rcpf(1.0f + e2);
        float val2 = (lane < 32) ? sg2 : fmaf(2.0f, sg2, -1.0f);
        float pr2  = __shfl_xor(val2, 32);
        if (lane < L2) {
            h2 = fmaf(val2, pr2 - h2, h2);
            hbuf[L1 + lane] = h2;
        }
    };
    auto compute_chunk = [&](const float* xbuf) {
        #pragma unroll 1
        for (int s = 0; s < CH; ++s) step(xbuf + s * FBINS);
    };

    // ---- software-pipelined chunk loop (even chunks in xA, odd in xB) ----
    load_stage(0); write_stage(xA);
    load_stage(1); write_stage(xB);
    load_stage(2);                       // invariant: stage holds chunk cp+2
    #pragma unroll 1
    for (int cp = 0; cp < NCHUNK - 1; cp += 2) {
        compute_chunk(xA);                           // chunk cp
        write_stage(xA);                             // <- chunk cp+2
        if (cp + 3 < NCHUNK) load_stage(cp + 3);
        compute_chunk(xB);                           // chunk cp+1
        if (cp + 3 < NCHUNK) write_stage(xB);        // <- chunk cp+3
        if (cp + 4 < NCHUNK) load_stage(cp + 4);
    }
    compute_chunk(xA);                               // final chunk 24

    // ---- FC3 (20->16) + ReLU, lanes 0..15, result -> hbuf[0..15] ----
    if (lane < L3) {
        float a3 = b3g[lane];
        #pragma unroll
        for (int k = 0; k < L2; ++k) a3 = fmaf(hbuf[L1 + k], w3[k * L3 + lane], a3);
        hbuf[lane] = fmaxf(a3, 0.0f);
    }
    // ---- FC4 (16->10), lanes 0..9, logits -> hbuf[40..49] ----
    if (lane < NCLASS) {
        float a4 = b4g[lane];
        #pragma unroll
        for (int k = 0; k < L3; ++k) a4 = fmaf(hbuf[k], w4[k * NCLASS + lane], a4);
        hbuf[40 + lane] = a4;
    }
    // ---- log_softmax over 10 logits (redundant per-lane, trivially cheap) ----
    float m = -1e30f;
    #pragma unroll
    for (int k = 0; k < NCLASS; ++k) m = fmaxf(m, hbuf[40 + k]);
    float ssum = 0.0f;
    #pragma unroll
    for (int k = 0; k < NCLASS; ++k)
        ssum += __builtin_amdgcn_exp2f((hbuf[40 + k] - m) * LOG2E);
    float lse = m + __builtin_amdgcn_logf(ssum) * LN2;
    if (lane < NCLASS) outg[b * NCLASS + lane] = hbuf[40 + lane] - lse;
}

extern "C" void kernel_launch(void* const* d_in, const int* in_sizes, int n_in,
                              void* d_out, int out_size, void* d_ws, size_t ws_size,
                              hipStream_t stream) {
    const float* x   = (const float*)d_in[0];
    const float* wz1 = (const float*)d_in[1];
    const float* bz1 = (const float*)d_in[2];
    const float* wh1 = (const float*)d_in[3];
    const float* bh1 = (const float*)d_in[4];
    const float* wz2 = (const float*)d_in[5];
    const float* bz2 = (const float*)d_in[6];
    const float* wh2 = (const float*)d_in[7];
    const float* bh2 = (const float*)d_in[8];
    const float* w3  = (const float*)d_in[9];
    const float* b3  = (const float*)d_in[10];
    const float* w4  = (const float*)d_in[11];
    const float* b4  = (const float*)d_in[12];
    float* out = (float*)d_out;

    const int Bsz = in_sizes[0] / (T * FBINS);   // 512

    gru_net_kernel<<<dim3(Bsz), dim3(64), 0, stream>>>(
        x, wz1, bz1, wh1, bh1, wz2, bz2, wh2, bh2, w3, b3, w4, b4, out);
}

// Round 2
// 459.934 us; speedup vs baseline: 1.5598x; 1.5598x over previous
//
#include <hip/hip_runtime.h>

// 2-layer GRU (T=1000 serial steps, B=512) + FC + log_softmax.
// Pass 1 (parallel): ax[b,t,0:32]=x@Wz1+bz1, ax[b,t,32:64]=x@Wh1+bh1  -> d_ws
// Pass 2 (latency-bound): 1 wave per batch element; h broadcast via v_readlane
// (SGPR operands, no LDS on the critical path); ax prefetched into registers.

constexpr int FBINS  = 40;
constexpr int L1     = 32;
constexpr int L2     = 20;
constexpr int L3     = 16;
constexpr int NCLASS = 10;
constexpr int T      = 1000;
constexpr float LOG2E = 1.4426950408889634f;
constexpr float LN2   = 0.6931471805599453f;

__device__ __forceinline__ float rl(float v, int l) {
    return __uint_as_float(__builtin_amdgcn_readlane(__float_as_uint(v), l));
}

// ---------------- pass 1: x-projection ----------------
constexpr int TCH = 100;   // timesteps per block
__global__ __launch_bounds__(256) void xproj_kernel(
    const float* __restrict__ xg,
    const float* __restrict__ wz1, const float* __restrict__ bz1,
    const float* __restrict__ wh1, const float* __restrict__ bh1,
    float* __restrict__ ax, int t0, int tcnt, int segcap)
{
    __shared__ float xs[TCH * FBINS];
    const int tid = threadIdx.x, lane = tid & 63;
    const int b   = blockIdx.x;
    const int lt0 = blockIdx.y * TCH;            // local t-offset in segment
    const int cnt = min(TCH, tcnt - lt0);
    const float* src = xg + ((size_t)b * T + t0 + lt0) * FBINS;
    const int ndw = cnt * FBINS;
    for (int i = tid; i < ndw; i += 256) xs[i] = src[i];
    __syncthreads();

    const int j = lane & 31;
    const float* wp = (lane < 32) ? wz1 : wh1;
    float w[FBINS];
    #pragma unroll
    for (int k = 0; k < FBINS; ++k) w[k] = wp[k * L1 + j];
    const float bias = (lane < 32) ? bz1[j] : bh1[j];

    const int wv = tid >> 6;
    for (int lt = wv; lt < cnt; lt += 4) {
        const float* xp = xs + lt * FBINS;
        float a0 = bias, a1 = 0.f, a2 = 0.f, a3 = 0.f;
        #pragma unroll
        for (int k = 0; k < FBINS; k += 4) {
            a0 = fmaf(xp[k+0], w[k+0], a0);
            a1 = fmaf(xp[k+1], w[k+1], a1);
            a2 = fmaf(xp[k+2], w[k+2], a2);
            a3 = fmaf(xp[k+3], w[k+3], a3);
        }
        ax[((size_t)b * segcap + lt0 + lt) * 64 + lane] = (a0 + a1) + (a2 + a3);
    }
}

// ---------------- pass 2: recurrence ----------------
constexpr int GS = 4;      // steps per prefetch group (double-buffered)
__global__ __launch_bounds__(64) void rec_kernel(
    const float* __restrict__ ax,
    const float* __restrict__ wz1, const float* __restrict__ wh1,
    const float* __restrict__ wz2, const float* __restrict__ bz2,
    const float* __restrict__ wh2, const float* __restrict__ bh2,
    const float* __restrict__ w3,  const float* __restrict__ b3,
    const float* __restrict__ w4,  const float* __restrict__ b4,
    float* __restrict__ hws, float* __restrict__ outg,
    int tcnt, int segcap, int first, int last)
{
    const int lane = threadIdx.x;
    const int b    = blockIdx.x;
    const int j    = lane & 31;

    // GRU1 h-part weight column (rows 40..71)
    float w1h[L1];
    {
        const float* wp = (lane < 32) ? wz1 : wh1;
        #pragma unroll
        for (int k = 0; k < L1; ++k) w1h[k] = wp[(FBINS + k) * L1 + j];
    }
    // GRU2 weight column (rows 0..51)
    float w2[L1 + L2]; float bias2;
    {
        const int jj = (j < L2) ? j : 0;
        const float* wp = (lane < 32) ? wz2 : wh2;
        #pragma unroll
        for (int k = 0; k < L1 + L2; ++k) w2[k] = wp[k * L2 + jj];
        bias2 = (lane < 32) ? bz2[jj] : bh2[jj];
    }

    float h1, h2;
    if (first) { h1 = 0.f; h2 = 0.f; }
    else {
        h1 = hws[b * 64 + j];
        h2 = hws[b * 64 + 32 + ((j < L2) ? j : 0)];
    }
    float sh1[L1], sh2[L2];           // wave-uniform copies (SGPR-resident)
    #pragma unroll
    for (int k = 0; k < L1; ++k) sh1[k] = rl(h1, k);
    #pragma unroll
    for (int k = 0; k < L2; ++k) sh2[k] = rl(h2, k);

    const float* axp = ax + (size_t)b * segcap * 64 + lane;

    auto step = [&](float axv) {
        // GRU1: acc = ax (x-part + bias, precomputed) + h1_prev @ W1h-col
        float a0 = axv, a1 = 0.f, a2 = 0.f, a3 = 0.f;
        #pragma unroll
        for (int k = 0; k < L1; k += 4) {
            a0 = fmaf(sh1[k+0], w1h[k+0], a0);
            a1 = fmaf(sh1[k+1], w1h[k+1], a1);
            a2 = fmaf(sh1[k+2], w1h[k+2], a2);
            a3 = fmaf(sh1[k+3], w1h[k+3], a3);
        }
        float acc = (a0 + a1) + (a2 + a3);
        float arg = (lane < 32) ? acc : (acc + acc);       // tanh via 2*sig(2a)-1
        float e   = __builtin_amdgcn_exp2f(-arg * LOG2E);
        float sg  = __builtin_amdgcn_rcpf(1.f + e);
        float val = (lane < 32) ? sg : fmaf(2.f, sg, -1.f);
        float pr  = __shfl_xor(val, 32);                   // z-lane gets g and v.v.
        h1 = fmaf(val, pr - h1, h1);                       // valid lanes<32
        #pragma unroll
        for (int k = 0; k < L1; ++k) sh1[k] = rl(h1, k);   // h1_new -> uniforms

        // GRU2: u2 = [h1_new(32), h2_prev(20)]
        float c0 = bias2, c1 = 0.f, c2 = 0.f, c3 = 0.f;
        #pragma unroll
        for (int k = 0; k < L1; k += 4) {
            c0 = fmaf(sh1[k+0], w2[k+0], c0);
            c1 = fmaf(sh1[k+1], w2[k+1], c1);
            c2 = fmaf(sh1[k+2], w2[k+2], c2);
            c3 = fmaf(sh1[k+3], w2[k+3], c3);
        }
        #pragma unroll
        for (int k = 0; k < L2; k += 4) {
            c0 = fmaf(sh2[k+0], w2[L1+k+0], c0);
            c1 = fmaf(sh2[k+1], w2[L1+k+1], c1);
            c2 = fmaf(sh2[k+2], w2[L1+k+2], c2);
            c3 = fmaf(sh2[k+3], w2[L1+k+3], c3);
        }
        float acc2 = (c0 + c1) + (c2 + c3);
        float arg2 = (lane < 32) ? acc2 : (acc2 + acc2);
        float e2   = __builtin_amdgcn_exp2f(-arg2 * LOG2E);
        float sg2  = __builtin_amdgcn_rcpf(1.f + e2);
        float val2 = (lane < 32) ? sg2 : fmaf(2.f, sg2, -1.f);
        float pr2  = __shfl_xor(val2, 32);
        h2 = fmaf(val2, pr2 - h2, h2);                     // valid lanes<20
        #pragma unroll
        for (int k = 0; k < L2; ++k) sh2[k] = rl(h2, k);
    };

    // double-buffered register prefetch of ax, GS steps per group
    float bufA[GS], bufB[GS];
    const int ng = tcnt / GS;   // tcnt multiple of 8 -> ng even
    #pragma unroll
    for (int i = 0; i < GS; ++i) bufA[i] = axp[(size_t)(0 * GS + i) * 64];
    #pragma unroll
    for (int i = 0; i < GS; ++i) bufB[i] = axp[(size_t)(1 * GS + i) * 64];
    #pragma unroll 1
    for (int gp = 0; gp < ng; gp += 2) {
        #pragma unroll
        for (int i = 0; i < GS; ++i) step(bufA[i]);
        if (gp + 2 < ng) {
            #pragma unroll
            for (int i = 0; i < GS; ++i) bufA[i] = axp[(size_t)((gp + 2) * GS + i) * 64];
        }
        #pragma unroll
        for (int i = 0; i < GS; ++i) step(bufB[i]);
        if (gp + 3 < ng) {
            #pragma unroll
            for (int i = 0; i < GS; ++i) bufB[i] = axp[(size_t)((gp + 3) * GS + i) * 64];
        }
    }

    if (!last) {
        if (lane < L1) hws[b * 64 + lane] = h1;
        if (lane < L2) hws[b * 64 + 32 + lane] = h2;
    } else {
        // FC3 (20->16) + ReLU in lanes 0..15
        float a3 = 0.f;
        if (lane < L3) {
            a3 = b3[lane];
            #pragma unroll
            for (int k = 0; k < L2; ++k) a3 = fmaf(sh2[k], w3[k * L3 + lane], a3);
            a3 = fmaxf(a3, 0.f);
        }
        float s3[L3];
        #pragma unroll
        for (int k = 0; k < L3; ++k) s3[k] = rl(a3, k);
        // FC4 (16->10) in lanes 0..9
        float a4 = 0.f;
        if (lane < NCLASS) {
            a4 = b4[lane];
            #pragma unroll
            for (int k = 0; k < L3; ++k) a4 = fmaf(s3[k], w4[k * NCLASS + lane], a4);
        }
        float s4[NCLASS];
        #pragma unroll
        for (int k = 0; k < NCLASS; ++k) s4[k] = rl(a4, k);
        float m = s4[0];
        #pragma unroll
        for (int k = 1; k < NCLASS; ++k) m = fmaxf(m, s4[k]);
        float ss = 0.f;
        #pragma unroll
        for (int k = 0; k < NCLASS; ++k)
            ss += __builtin_amdgcn_exp2f((s4[k] - m) * LOG2E);
        float lse = m + __builtin_amdgcn_logf(ss) * LN2;
        if (lane < NCLASS) outg[b * NCLASS + lane] = s4[lane] - lse;
    }
}

extern "C" void kernel_launch(void* const* d_in, const int* in_sizes, int n_in,
                              void* d_out, int out_size, void* d_ws, size_t ws_size,
                              hipStream_t stream) {
    const float* x   = (const float*)d_in[0];
    const float* wz1 = (const float*)d_in[1];
    const float* bz1 = (const float*)d_in[2];
    const float* wh1 = (const float*)d_in[3];
    const float* bh1 = (const float*)d_in[4];
    const float* wz2 = (const float*)d_in[5];
    const float* bz2 = (const float*)d_in[6];
    const float* wh2 = (const float*)d_in[7];
    const float* bh2 = (const float*)d_in[8];
    const float* w3  = (const float*)d_in[9];
    const float* b3  = (const float*)d_in[10];
    const float* w4  = (const float*)d_in[11];
    const float* b4  = (const float*)d_in[12];
    float* out = (float*)d_out;

    const int Bsz = in_sizes[0] / (T * FBINS);          // 512

    float* hws = (float*)d_ws;                          // Bsz*64 floats of h state
    float* axw = hws + (size_t)Bsz * 64;                // ax segment buffer
    const size_t hbytes = (size_t)Bsz * 64 * sizeof(float);
    const size_t per_t  = (size_t)Bsz * 64 * sizeof(float);

    int segT = T;
    if (ws_size < hbytes + (size_t)T * per_t) {
        size_t avail = (ws_size > hbytes) ? ws_size - hbytes : 0;
        size_t s = avail / per_t;
        segT = (s > (size_t)T) ? T : (int)s;
        segT &= ~7;                                     // multiple of 8
        if (segT < 8) segT = 8;                         // last resort
    }

    for (int t0 = 0; t0 < T; t0 += segT) {
        const int tc = (T - t0 < segT) ? (T - t0) : segT;   // stays multiple of 8
        dim3 g1(Bsz, (tc + TCH - 1) / TCH);
        xproj_kernel<<<g1, dim3(256), 0, stream>>>(x, wz1, bz1, wh1, bh1,
                                                   axw, t0, tc, segT);
        rec_kernel<<<dim3(Bsz), dim3(64), 0, stream>>>(axw,
            wz1, wh1, wz2, bz2, wh2, bh2, w3, b3, w4, b4,
            hws, out, tc, segT, t0 == 0 ? 1 : 0, (t0 + tc >= T) ? 1 : 0);
    }
}

// Round 3
// 394.086 us; speedup vs baseline: 1.8205x; 1.1671x over previous
//
#include <hip/hip_runtime.h>

// 2-layer GRU (T=1000 serial, B=512) + FC + log_softmax.
// Pass 1: ax[b,t] = x_t @ W1x + b1 for both gates, stored as per-lane (z,g)
//         float2 pairs -> d_ws.
// Pass 2: one wave per batch element, SKEWED pipeline: lanes 0..31 run GRU1
//         unit j at step t while lanes 32..51 run GRU2 unit j at step t-1.
//         Both consume the same sh1(t-1)/sh2(t-2) uniform broadcasts
//         (v_readlane -> SGPR), so one 104-FMA stream drives both layers.
//         No shfl/bpermute/LDS on the critical path.

constexpr int FBINS  = 40;
constexpr int L1     = 32;
constexpr int L2     = 20;
constexpr int L3     = 16;
constexpr int NCLASS = 10;
constexpr int T      = 1000;
constexpr int KTOT   = L1 + L2;   // 52
constexpr float LOG2E = 1.4426950408889634f;
constexpr float LN2   = 0.6931471805599453f;

__device__ __forceinline__ float rl(float v, int l) {
    return __uint_as_float(__builtin_amdgcn_readlane(__float_as_uint(v), l));
}

// ---------------- pass 1: x-projection ----------------
constexpr int TCH = 100;   // timesteps per block
__global__ __launch_bounds__(256) void xproj_kernel(
    const float* __restrict__ xg,
    const float* __restrict__ wz1, const float* __restrict__ bz1,
    const float* __restrict__ wh1, const float* __restrict__ bh1,
    float* __restrict__ ax, int t0, int tcnt, int segcap)
{
    __shared__ float xs[TCH * FBINS];
    const int tid = threadIdx.x, lane = tid & 63;
    const int b   = blockIdx.x;
    const int lt0 = blockIdx.y * TCH;
    const int cnt = min(TCH, tcnt - lt0);
    const float* src = xg + ((size_t)b * T + t0 + lt0) * FBINS;
    const int ndw = cnt * FBINS;
    for (int i = tid; i < ndw; i += 256) xs[i] = src[i];
    __syncthreads();

    const int j = lane & 31;
    const float* wp = (lane < 32) ? wz1 : wh1;   // lane<32: z-gate, else g-gate
    float w[FBINS];
    #pragma unroll
    for (int k = 0; k < FBINS; ++k) w[k] = wp[k * L1 + j];
    const float bias = (lane < 32) ? bz1[j] : bh1[j];
    const int slot = j * 2 + (lane >> 5);        // (z,g) interleaved pairs

    const int wv = tid >> 6;
    for (int lt = wv; lt < cnt; lt += 4) {
        const float* xp = xs + lt * FBINS;
        float a0 = bias, a1 = 0.f, a2 = 0.f, a3 = 0.f;
        #pragma unroll
        for (int k = 0; k < FBINS; k += 4) {
            a0 = fmaf(xp[k+0], w[k+0], a0);
            a1 = fmaf(xp[k+1], w[k+1], a1);
            a2 = fmaf(xp[k+2], w[k+2], a2);
            a3 = fmaf(xp[k+3], w[k+3], a3);
        }
        ax[((size_t)b * segcap + lt0 + lt) * 64 + slot] = (a0 + a1) + (a2 + a3);
    }
}

// ---------------- pass 2: skewed recurrence ----------------
constexpr int GS = 4;      // steps per prefetch group (double-buffered)
__global__ __launch_bounds__(64) void rec_kernel(
    const float* __restrict__ ax,
    const float* __restrict__ wz1, const float* __restrict__ wh1,
    const float* __restrict__ wz2, const float* __restrict__ bz2,
    const float* __restrict__ wh2, const float* __restrict__ bh2,
    const float* __restrict__ w3,  const float* __restrict__ b3,
    const float* __restrict__ w4,  const float* __restrict__ b4,
    float* __restrict__ hws, float* __restrict__ outg,
    int tcnt, int segcap, int first, int last)
{
    const int lane = threadIdx.x;
    const int b    = blockIdx.x;
    const int j    = lane & 31;
    const bool lo  = lane < 32;
    const int j2   = (j < L2) ? j : 0;           // clamp for lanes 52..63 (junk)

    // Per-lane weight columns. Lower: GRU1 h-part (rows 40..71 of w_*x1).
    // Upper: GRU2 full (rows 0..51 of w_*x2). sh2-part rows are zero for lower.
    float wZ[KTOT], wG[KTOT];
    #pragma unroll
    for (int k = 0; k < L1; ++k) {
        wZ[k] = lo ? wz1[(FBINS + k) * L1 + j] : wz2[k * L2 + j2];
        wG[k] = lo ? wh1[(FBINS + k) * L1 + j] : wh2[k * L2 + j2];
    }
    #pragma unroll
    for (int k = 0; k < L2; ++k) {
        wZ[L1 + k] = lo ? 0.f : wz2[(L1 + k) * L2 + j2];
        wG[L1 + k] = lo ? 0.f : wh2[(L1 + k) * L2 + j2];
    }
    const float initZ = lo ? 0.f : bz2[j2];
    const float initG = lo ? 0.f : bh2[j2];

    const float h_up0 = first ? 0.f : hws[b * 64 + 32 + j2];   // h2 restore
    float h = lo ? (first ? 0.f : hws[b * 64 + j]) : h_up0;

    float sh[KTOT];                     // uniform broadcasts (SGPR-resident)
    #pragma unroll
    for (int k = 0; k < L1; ++k) sh[k] = rl(h, k);
    #pragma unroll
    for (int k = 0; k < L2; ++k) sh[L1 + k] = rl(h, 32 + k);

    const float2* axp = (const float2*)ax + (size_t)b * segcap * 32 + j;

    auto step = [&](float2 axv) {
        float az = lo ? axv.x : initZ;
        float ag = lo ? axv.y : initG;
        float z0 = az, z1 = 0.f, z2 = 0.f, z3 = 0.f;
        float g0 = ag, g1 = 0.f, g2 = 0.f, g3 = 0.f;
        #pragma unroll
        for (int k = 0; k < KTOT; k += 4) {
            z0 = fmaf(sh[k+0], wZ[k+0], z0);
            z1 = fmaf(sh[k+1], wZ[k+1], z1);
            z2 = fmaf(sh[k+2], wZ[k+2], z2);
            z3 = fmaf(sh[k+3], wZ[k+3], z3);
            g0 = fmaf(sh[k+0], wG[k+0], g0);
            g1 = fmaf(sh[k+1], wG[k+1], g1);
            g2 = fmaf(sh[k+2], wG[k+2], g2);
            g3 = fmaf(sh[k+3], wG[k+3], g3);
        }
        float z = (z0 + z1) + (z2 + z3);
        float g = (g0 + g1) + (g2 + g3);
        float ez = __builtin_amdgcn_exp2f(-z * LOG2E);        // sigmoid(z)
        float s  = __builtin_amdgcn_rcpf(1.f + ez);
        float eg = __builtin_amdgcn_exp2f(-2.f * g * LOG2E);  // tanh(g)
        float r  = __builtin_amdgcn_rcpf(1.f + eg);
        float gt = fmaf(2.f, r, -1.f);
        h = fmaf(s, gt - h, h);                               // (1-z)h + z*g
        #pragma unroll
        for (int k = 0; k < L1; ++k) sh[k] = rl(h, k);
        #pragma unroll
        for (int k = 0; k < L2; ++k) sh[L1 + k] = rl(h, 32 + k);
    };

    // ---- pipelined loop, GS-step groups, double-buffered register prefetch
    float2 bufA[GS], bufB[GS];
    const int ng = tcnt / GS;                    // tcnt multiple of 8 -> even
    #pragma unroll
    for (int i = 0; i < GS; ++i) bufA[i] = axp[(size_t)i * 32];
    #pragma unroll
    for (int i = 0; i < GS; ++i) bufB[i] = axp[(size_t)(GS + i) * 32];

    // group 0: iteration 0 computes GRU1(0) + a discarded upper step; fix up.
    step(bufA[0]);
    h = lo ? h : h_up0;                          // restore h2 state
    #pragma unroll
    for (int k = 0; k < L2; ++k) sh[L1 + k] = rl(h, 32 + k);
    #pragma unroll
    for (int i = 1; i < GS; ++i) step(bufA[i]);
    if (2 < ng) {
        #pragma unroll
        for (int i = 0; i < GS; ++i) bufA[i] = axp[(size_t)(2 * GS + i) * 32];
    }
    #pragma unroll 1
    for (int gp = 1; gp < ng; gp += 2) {
        #pragma unroll
        for (int i = 0; i < GS; ++i) step(bufB[i]);
        if (gp + 2 < ng) {
            #pragma unroll
            for (int i = 0; i < GS; ++i) bufB[i] = axp[(size_t)((gp + 2) * GS + i) * 32];
        }
        if (gp + 1 < ng) {
            #pragma unroll
            for (int i = 0; i < GS; ++i) step(bufA[i]);
            if (gp + 3 < ng) {
                #pragma unroll
                for (int i = 0; i < GS; ++i) bufA[i] = axp[(size_t)((gp + 3) * GS + i) * 32];
            }
        }
    }

    // lower h = h1(tcnt-1): save before the epilogue junks it
    if (!last && lo) hws[b * 64 + j] = h;

    // epilogue: completes GRU2(tcnt-1) on upper lanes (lower result unused)
    step(make_float2(0.f, 0.f));

    if (!last) {
        if (!lo && j < L2) hws[b * 64 + 32 + j] = h;
        return;
    }

    // ---- FC3 (20->16) + ReLU ----
    float a3 = 0.f;
    if (lane < L3) {
        a3 = b3[lane];
        #pragma unroll
        for (int k = 0; k < L2; ++k) a3 = fmaf(sh[L1 + k], w3[k * L3 + lane], a3);
        a3 = fmaxf(a3, 0.f);
    }
    float s3[L3];
    #pragma unroll
    for (int k = 0; k < L3; ++k) s3[k] = rl(a3, k);
    // ---- FC4 (16->10) ----
    float a4 = 0.f;
    if (lane < NCLASS) {
        a4 = b4[lane];
        #pragma unroll
        for (int k = 0; k < L3; ++k) a4 = fmaf(s3[k], w4[k * NCLASS + lane], a4);
    }
    float s4[NCLASS];
    #pragma unroll
    for (int k = 0; k < NCLASS; ++k) s4[k] = rl(a4, k);
    float m = s4[0];
    #pragma unroll
    for (int k = 1; k < NCLASS; ++k) m = fmaxf(m, s4[k]);
    float ss = 0.f;
    #pragma unroll
    for (int k = 0; k < NCLASS; ++k)
        ss += __builtin_amdgcn_exp2f((s4[k] - m) * LOG2E);
    float lse = m + __builtin_amdgcn_logf(ss) * LN2;
    if (lane < NCLASS) outg[b * NCLASS + lane] = s4[lane] - lse;
}

extern "C" void kernel_launch(void* const* d_in, const int* in_sizes, int n_in,
                              void* d_out, int out_size, void* d_ws, size_t ws_size,
                              hipStream_t stream) {
    const float* x   = (const float*)d_in[0];
    const float* wz1 = (const float*)d_in[1];
    const float* bz1 = (const float*)d_in[2];
    const float* wh1 = (const float*)d_in[3];
    const float* bh1 = (const float*)d_in[4];
    const float* wz2 = (const float*)d_in[5];
    const float* bz2 = (const float*)d_in[6];
    const float* wh2 = (const float*)d_in[7];
    const float* bh2 = (const float*)d_in[8];
    const float* w3  = (const float*)d_in[9];
    const float* b3  = (const float*)d_in[10];
    const float* w4  = (const float*)d_in[11];
    const float* b4  = (const float*)d_in[12];
    float* out = (float*)d_out;

    const int Bsz = in_sizes[0] / (T * FBINS);          // 512

    float* hws = (float*)d_ws;                          // Bsz*64 floats h state
    float* axw = hws + (size_t)Bsz * 64;
    const size_t hbytes = (size_t)Bsz * 64 * sizeof(float);
    const size_t per_t  = (size_t)Bsz * 64 * sizeof(float);

    int segT = T;
    if (ws_size < hbytes + (size_t)T * per_t) {
        size_t avail = (ws_size > hbytes) ? ws_size - hbytes : 0;
        size_t s = avail / per_t;
        segT = (s > (size_t)T) ? T : (int)s;
        segT &= ~7;
        if (segT < 8) segT = 8;
    }

    for (int t0 = 0; t0 < T; t0 += segT) {
        const int tc = (T - t0 < segT) ? (T - t0) : segT;
        dim3 g1(Bsz, (tc + TCH - 1) / TCH);
        xproj_kernel<<<g1, dim3(256), 0, stream>>>(x, wz1, bz1, wh1, bh1,
                                                   axw, t0, tc, segT);
        rec_kernel<<<dim3(Bsz), dim3(64), 0, stream>>>(axw,
            wz1, wh1, wz2, bz2, wh2, bh2, w3, b3, w4, b4,
            hws, out, tc, segT, t0 == 0 ? 1 : 0, (t0 + tc >= T) ? 1 : 0);
    }
}